// Round 1
// baseline (164.513 us; speedup 1.0000x reference)
//
#include <hip/hip_runtime.h>
#include <hip/hip_bf16.h>
#include <stdint.h>

#define NN 8192
#define DD 128

// bucketing: bucket = s >> 5  (256 buckets of 32 rows)
#define NBUCK 256
#define ROWMASK 31
#define BSHIFT 5
#define CAPM 4096          // mask edges per bucket (mean 2048)
#define CAPE 2048          // e1/e2 edges per bucket (mean 1024)
#define CSTRIDE 16         // cursor padding: one counter per 64B line
#define LCAP 32768         // global passer-list capacity

typedef __bf16 bf16x8 __attribute__((ext_vector_type(8)));
typedef float  f32x4  __attribute__((ext_vector_type(4)));

// ---- kernel 1: fused  M = Wq^T @ Wk  (blocks 0..63)  +  edge bucketing ----
__global__ __launch_bounds__(256) void bucket_scatter(
    const int* __restrict__ ei1, int e1,
    const int* __restrict__ ei2, int e2,
    const int* __restrict__ mask, int em,
    const float* __restrict__ Wq, const float* __restrict__ Wk,
    float* __restrict__ M,
    int2* __restrict__ bm, int2* __restrict__ b1, int2* __restrict__ b2,
    int* __restrict__ cursors) {
    if (blockIdx.x < 64) {
        int c = blockIdx.x * 2 + (threadIdx.x >> 7);
        int e = threadIdx.x & 127;
        float acc = 0.f;
#pragma unroll 8
        for (int a = 0; a < DD; ++a)
            acc += Wq[a * DD + c] * Wk[a * DD + e];
        M[c * DD + e] = acc;
        return;
    }
    int t = (blockIdx.x - 64) * 256 + threadIdx.x;
    const int* src; int e, list, ne, cap; int2* dst;
    if (t < em) {
        src = mask; e = t; list = 0; ne = em; dst = bm; cap = CAPM;
    } else if (t < em + e1) {
        src = ei1; e = t - em; list = 1; ne = e1; dst = b1; cap = CAPE;
    } else if (t < em + e1 + e2) {
        src = ei2; e = t - em - e1; list = 2; ne = e2; dst = b2; cap = CAPE;
    } else return;
    int s = src[e];
    int d = src[ne + e];
    int b = s >> BSHIFT;
    int pos = atomicAdd(&cursors[(list * NBUCK + b) * CSTRIDE], 1);
    if (pos < cap) dst[b * cap + pos] = make_int2(s, d);
}

// ---- kernel 2: per-bucket LDS-bitmap filter -------------------------------
__global__ __launch_bounds__(1024) void bucket_filter(
    const int2* __restrict__ bm, const int2* __restrict__ b1,
    const int2* __restrict__ b2, const int* __restrict__ cursors,
    int2* __restrict__ l1, int* __restrict__ c1,
    int2* __restrict__ l2, int* __restrict__ c2) {
    __shared__ uint32_t maskbm[8192];   // 32 rows x 8192 cols bits = 32 KB
    __shared__ uint32_t seenbm[8192];   // dedup bitmap, 32 KB
    int b = blockIdx.x;
    int t = threadIdx.x;
    int nm = min(cursors[b * CSTRIDE], CAPM);
    int n1 = min(cursors[(NBUCK + b) * CSTRIDE], CAPE);
    int n2 = min(cursors[(2 * NBUCK + b) * CSTRIDE], CAPE);

    for (int i = t; i < 8192; i += 1024) { maskbm[i] = 0; seenbm[i] = 0; }
    __syncthreads();

    // build mask bitmap in LDS (duplicates harmless)
    for (int i = t; i < nm; i += 1024) {
        int2 sd = bm[b * CAPM + i];
        uint32_t idx = (uint32_t)(sd.x & ROWMASK) * (uint32_t)NN + (uint32_t)sd.y;
        atomicOr(&maskbm[idx >> 5], 1u << (idx & 31));
    }
    __syncthreads();

    // probe e1, dedup via seen
    for (int i = t; i < n1; i += 1024) {
        int2 sd = b1[b * CAPE + i];
        uint32_t idx = (uint32_t)(sd.x & ROWMASK) * (uint32_t)NN + (uint32_t)sd.y;
        uint32_t m = 1u << (idx & 31);
        if (maskbm[idx >> 5] & m) {
            uint32_t old = atomicOr(&seenbm[idx >> 5], m);
            if (!(old & m)) {
                int p = atomicAdd(c1, 1);
                if (p < LCAP) l1[p] = sd;
            }
        }
    }
    __syncthreads();
    for (int i = t; i < 8192; i += 1024) seenbm[i] = 0;
    __syncthreads();

    // probe e2
    for (int i = t; i < n2; i += 1024) {
        int2 sd = b2[b * CAPE + i];
        uint32_t idx = (uint32_t)(sd.x & ROWMASK) * (uint32_t)NN + (uint32_t)sd.y;
        uint32_t m = 1u << (idx & 31);
        if (maskbm[idx >> 5] & m) {
            uint32_t old = atomicOr(&seenbm[idx >> 5], m);
            if (!(old & m)) {
                int p = atomicAdd(c2, 1);
                if (p < LCAP) l2[p] = sd;
            }
        }
    }
}

// ---- scatter (unchanged logic) --------------------------------------------
__device__ inline void scatter_a1_body(const int2* __restrict__ list, int n,
                                       const float* __restrict__ x,
                                       float* __restrict__ z,
                                       int b0, int nb) {
    int c = threadIdx.x;
    for (int e = b0; e < n; e += nb) {
        int2 sd = list[e];
        atomicAdd(&z[sd.y * DD + c], x[sd.x * DD + c]);
    }
}

__device__ inline void scatter_a2_body(const int2* __restrict__ list, int n,
                                       const float* __restrict__ x,
                                       const float* __restrict__ M,
                                       const float* __restrict__ Wv,
                                       float* __restrict__ x2,
                                       int b0, int nb,
                                       float* xs, float* xd, float* red) {
    int c = threadIdx.x;
    for (int e = b0; e < n; e += nb) {
        int2 sd = list[e];            // s = source j, d = target i
        __syncthreads();
        xs[c] = x[sd.x * DD + c];
        xd[c] = x[sd.y * DD + c];
        __syncthreads();
        float acc = 0.f;
#pragma unroll 8
        for (int a = 0; a < DD; ++a)
            acc += xd[a] * M[a * DD + c];
        float part = acc * xs[c];
        for (int off = 32; off; off >>= 1)
            part += __shfl_down(part, off, 64);
        if ((c & 63) == 0) red[c >> 6] = part;
        __syncthreads();
        float s_e = red[0] + red[1];
        float v = 0.f;
#pragma unroll 8
        for (int b = 0; b < DD; ++b)
            v += Wv[c * DD + b] * xs[b];
        atomicAdd(&x2[sd.y * DD + c], s_e * v);
    }
}

__global__ void scatter_both(const int2* __restrict__ l1, const int* __restrict__ c1,
                             const int2* __restrict__ l2, const int* __restrict__ c2,
                             const float* __restrict__ x, const float* __restrict__ M,
                             const float* __restrict__ Wv,
                             float* __restrict__ z, float* __restrict__ x2) {
    __shared__ float xs[DD], xd[DD], red[2];
    if (blockIdx.x < 1024) {
        scatter_a1_body(l1, *c1, x, z, blockIdx.x, 1024);
    } else {
        scatter_a2_body(l2, *c2, x, M, Wv, x2, blockIdx.x - 1024, 1024, xs, xd, red);
    }
}

// ---- epilogue (unchanged) --------------------------------------------------
__device__ inline bf16x8 ld_bf16x8(const float* __restrict__ p) {
    float4 u0 = *(const float4*)p;
    float4 u1 = *(const float4*)(p + 4);
    bf16x8 r;
    r[0] = (__bf16)u0.x; r[1] = (__bf16)u0.y; r[2] = (__bf16)u0.z; r[3] = (__bf16)u0.w;
    r[4] = (__bf16)u1.x; r[5] = (__bf16)u1.y; r[6] = (__bf16)u1.z; r[7] = (__bf16)u1.w;
    return r;
}

__global__ __launch_bounds__(256) void epilogue_mfma(
    const float* __restrict__ x, const float* __restrict__ z,
    const float* __restrict__ x2,
    const float* __restrict__ Wg0, const float* __restrict__ Wg1,
    const int* __restrict__ cnt2, float inv_np1, float coef_x,
    float* __restrict__ out) {
    int lane = threadIdx.x & 63;
    int wave = threadIdx.x >> 6;       // 0..3 -> 32-col strip
    int i16  = lane & 15;
    int kg   = lane >> 4;              // k-group of 8
    int rowbase = blockIdx.x * 16;
    int colbase = wave * 32;

    f32x4 acc[2] = {};
#pragma unroll
    for (int kk = 0; kk < 8; ++kk) {
        const float* src = (kk < 4) ? x : z;
        const float* W   = (kk < 4) ? Wg0 : Wg1;
        int kofs = (kk & 3) * 32 + kg * 8;
        bf16x8 a  = ld_bf16x8(src + (rowbase + i16) * DD + kofs);
        bf16x8 b0 = ld_bf16x8(W + (colbase +      i16) * DD + kofs);
        bf16x8 b1 = ld_bf16x8(W + (colbase + 16 + i16) * DD + kofs);
        acc[0] = __builtin_amdgcn_mfma_f32_16x16x32_bf16(a, b0, acc[0], 0, 0, 0);
        acc[1] = __builtin_amdgcn_mfma_f32_16x16x32_bf16(a, b1, acc[1], 0, 0, 0);
    }
    float scale2 = (float)NN / (float)(*cnt2);
#pragma unroll
    for (int t = 0; t < 2; ++t)
#pragma unroll
        for (int r = 0; r < 4; ++r) {
            int row = rowbase + kg * 4 + r;
            int col = colbase + t * 16 + i16;
            float xv  = x[row * DD + col];
            float x2v = x2[row * DD + col];
            out[row * DD + col] = acc[t][r] * inv_np1 + coef_x * xv - x2v * scale2;
        }
}

// ---- host ------------------------------------------------------------------

extern "C" void kernel_launch(void* const* d_in, const int* in_sizes, int n_in,
                              void* d_out, int out_size, void* d_ws, size_t ws_size,
                              hipStream_t stream) {
    const float* x   = (const float*)d_in[0];
    const int* ei1   = (const int*)d_in[1];
    const int* ei2   = (const int*)d_in[2];
    const int* mask  = (const int*)d_in[3];
    const float* Wg0 = (const float*)d_in[4];
    const float* Wg1 = (const float*)d_in[5];
    const float* Wq  = (const float*)d_in[6];
    const float* Wk  = (const float*)d_in[7];
    const float* Wv  = (const float*)d_in[8];
    float* out = (float*)d_out;

    int e1 = in_sizes[1] / 2;
    int e2 = in_sizes[2] / 2;
    int em = in_sizes[3] / 2;
    float np1 = (float)em / (float)NN;   // 64.0 here
    float inv1 = 1.0f / np1;
    float coefx = (np1 - 1.0f) * inv1;

    char* ws = (char*)d_ws;

    // layout (all offsets 64B-aligned)
    const size_t O_Z    = 0;                       // 4 MB   (zeroed)
    const size_t O_X2   = 4194304;                 // 4 MB   (zeroed)
    const size_t O_CUR  = 8388608;                 // 768*16*4 = 49152 (zeroed)
    const size_t O_CNT  = 8437760;                 // c1,c2 (+pad to 64) (zeroed)
    const size_t O_M    = 8437824;                 // 64 KB
    const size_t O_BM   = 8503360;                 // 256*4096*8 = 8 MB
    const size_t O_B1   = 16891968;                // 256*2048*8 = 4 MB
    const size_t O_B2   = 21086272;                // 4 MB
    const size_t O_L1   = 25280576;                // 32768*8 = 256 KB
    const size_t O_L2   = 25542720;                // 256 KB
    // end = 25804864 (~24.6 MB)

    float*    z     = (float*)(ws + O_Z);
    float*    x2acc = (float*)(ws + O_X2);
    int*      curs  = (int*)(ws + O_CUR);
    int*      c1    = (int*)(ws + O_CNT);
    int*      c2    = (int*)(ws + O_CNT + 4);
    float*    M     = (float*)(ws + O_M);
    int2*     bm    = (int2*)(ws + O_BM);
    int2*     b1    = (int2*)(ws + O_B1);
    int2*     b2    = (int2*)(ws + O_B2);
    int2*     l1    = (int2*)(ws + O_L1);
    int2*     l2    = (int2*)(ws + O_L2);

    // zero z, x2, cursors, counters in one memset (bucket arrays need no clear)
    hipMemsetAsync(ws, 0, O_M, stream);

    int tot = em + e1 + e2;
    bucket_scatter<<<64 + (tot + 255) / 256, 256, 0, stream>>>(
        ei1, e1, ei2, e2, mask, em, Wq, Wk, M, bm, b1, b2, curs);
    bucket_filter<<<NBUCK, 1024, 0, stream>>>(bm, b1, b2, curs, l1, c1, l2, c2);
    scatter_both<<<2048, DD, 0, stream>>>(l1, c1, l2, c2, x, M, Wv, z, x2acc);
    epilogue_mfma<<<NN / 16, 256, 0, stream>>>(x, z, x2acc, Wg0, Wg1, c2,
                                               inv1, coefx, out);
}

// Round 2
// 74.393 us; speedup vs baseline: 2.2114x; 2.2114x over previous
//
#include <hip/hip_runtime.h>
#include <hip/hip_bf16.h>
#include <stdint.h>

#define NN 8192
#define DD 128

// bucketing: bucket = s >> 5  (256 buckets of 32 rows)
#define NBUCK 256
#define ROWMASK 31
#define BSHIFT 5
#define CAPM 4096          // mask edges per bucket (mean 2048)
#define CAPE 2048          // e1/e2 edges per bucket (mean 1024)
#define CSTRIDE 16         // cursor padding: one counter per 64B line
#define LCAP 32768         // global passer-list capacity

// partition params
#define CHUNK 4096
#define TPB 256            // == NBUCK (scan uses all threads)
#define EPT 16             // edges per thread: CHUNK / TPB

#define PCAP 256           // per-block passer staging in filter

typedef __bf16 bf16x8 __attribute__((ext_vector_type(8)));
typedef float  f32x4  __attribute__((ext_vector_type(4)));

// ---- kernel 1: fused  M = Wq^T @ Wk  (blocks 0..63)  +  radix partition ---
__global__ __launch_bounds__(256) void partition_gemm(
    const int* __restrict__ ei1, int e1,
    const int* __restrict__ ei2, int e2,
    const int* __restrict__ mask, int em,
    const float* __restrict__ Wq, const float* __restrict__ Wk,
    float* __restrict__ M,
    int2* __restrict__ bm, int2* __restrict__ b1, int2* __restrict__ b2,
    int* __restrict__ cursors, int nbm, int nb1, int nb2) {
    if (blockIdx.x < 64) {
        int c = blockIdx.x * 2 + (threadIdx.x >> 7);
        int e = threadIdx.x & 127;
        float acc = 0.f;
#pragma unroll 8
        for (int a = 0; a < DD; ++a)
            acc += Wq[a * DD + c] * Wk[a * DD + e];
        M[c * DD + e] = acc;
        return;
    }
    int pb = blockIdx.x - 64;
    const int* src; int ne; int2* dst; int cap; int list; int chunk0;
    if (pb < nbm)            { src = mask; ne = em; dst = bm; cap = CAPM; list = 0; chunk0 = pb; }
    else if (pb < nbm + nb1) { src = ei1;  ne = e1; dst = b1; cap = CAPE; list = 1; chunk0 = pb - nbm; }
    else if (pb < nbm + nb1 + nb2) { src = ei2; ne = e2; dst = b2; cap = CAPE; list = 2; chunk0 = pb - nbm - nb1; }
    else return;

    int base = chunk0 * CHUNK;
    int n = ne - base;
    if (n > CHUNK) n = CHUNK;
    if (n <= 0) return;
    int t = threadIdx.x;

    __shared__ int cnt[NBUCK];
    __shared__ int sc[2][NBUCK];
    __shared__ int startS[NBUCK];
    __shared__ int gbase[NBUCK];
    __shared__ int cur[NBUCK];
    __shared__ int2 stage[CHUNK];

    cnt[t] = 0;
    __syncthreads();

    int ss[EPT], dd2[EPT];
#pragma unroll
    for (int k = 0; k < EPT; ++k) {
        int i = t + k * TPB;
        if (i < n) {
            int e = base + i;
            ss[k]  = src[e];
            dd2[k] = src[ne + e];
            atomicAdd(&cnt[ss[k] >> BSHIFT], 1);
        } else ss[k] = -1;
    }
    __syncthreads();

    // inclusive scan over 256 bucket counts (256 threads)
    sc[0][t] = cnt[t];
    __syncthreads();
    int sb = 0;
    for (int off = 1; off < NBUCK; off <<= 1) {
        int d = sb ^ 1;
        sc[d][t] = (t >= off) ? sc[sb][t] + sc[sb][t - off] : sc[sb][t];
        sb = d;
        __syncthreads();
    }
    int startv = (t == 0) ? 0 : sc[sb][t - 1];
    startS[t] = startv;
    cur[t]    = startv;
    gbase[t]  = atomicAdd(&cursors[(list * NBUCK + t) * CSTRIDE], cnt[t]);
    __syncthreads();

    // scatter into bucket-sorted LDS staging
#pragma unroll
    for (int k = 0; k < EPT; ++k) {
        if (ss[k] >= 0) {
            int b = ss[k] >> BSHIFT;
            int p = atomicAdd(&cur[b], 1);
            stage[p] = make_int2(ss[k], dd2[k]);
        }
    }
    __syncthreads();

    // coalesced flush: contiguous runs per bucket
    for (int i = t; i < n; i += TPB) {
        int2 it = stage[i];
        int b = it.x >> BSHIFT;
        int off = gbase[b] + (i - startS[b]);
        if (off < cap) dst[b * cap + off] = it;
    }
}

// ---- kernel 2: per-bucket LDS-bitmap filter -------------------------------
__global__ __launch_bounds__(1024) void bucket_filter(
    const int2* __restrict__ bm, const int2* __restrict__ b1,
    const int2* __restrict__ b2, const int* __restrict__ cursors,
    int2* __restrict__ l1, int* __restrict__ c1,
    int2* __restrict__ l2, int* __restrict__ c2) {
    __shared__ uint32_t bmap[8192];   // 32 rows x 8192 cols bits = 32 KB
    __shared__ int2 pass[PCAP];
    __shared__ int pc, pbase;
    int b = blockIdx.x;
    int t = threadIdx.x;
    int nm = min(cursors[b * CSTRIDE], CAPM);
    int n1 = min(cursors[(NBUCK + b) * CSTRIDE], CAPE);
    int n2 = min(cursors[(2 * NBUCK + b) * CSTRIDE], CAPE);

    for (int i = t; i < 8192; i += 1024) bmap[i] = 0;
    if (t == 0) pc = 0;
    __syncthreads();

    // build mask bitmap in LDS (duplicates harmless)
    for (int i = t; i < nm; i += 1024) {
        int2 sd = bm[b * CAPM + i];
        uint32_t idx = (uint32_t)(sd.x & ROWMASK) * (uint32_t)NN + (uint32_t)sd.y;
        atomicOr(&bmap[idx >> 5], 1u << (idx & 31));
    }
    __syncthreads();

    // probe e1; dedup by clear-on-pass (first clearer wins)
    for (int i = t; i < n1; i += 1024) {
        int2 sd = b1[b * CAPE + i];
        uint32_t idx = (uint32_t)(sd.x & ROWMASK) * (uint32_t)NN + (uint32_t)sd.y;
        uint32_t m = 1u << (idx & 31);
        if (bmap[idx >> 5] & m) {
            uint32_t old = atomicAnd(&bmap[idx >> 5], ~m);
            if (old & m) {
                int p = atomicAdd(&pc, 1);
                if (p < PCAP) pass[p] = sd;
            }
        }
    }
    __syncthreads();
    if (t == 0) {
        int k = min(pc, PCAP);
        pbase = atomicAdd(c1, k);
        pc = k;
    }
    __syncthreads();
    for (int i = t; i < pc; i += 1024) {
        int p = pbase + i;
        if (p < LCAP) l1[p] = pass[i];
    }
    __syncthreads();
    if (t == 0) pc = 0;
    // rebuild cleared mask bits
    for (int i = t; i < nm; i += 1024) {
        int2 sd = bm[b * CAPM + i];
        uint32_t idx = (uint32_t)(sd.x & ROWMASK) * (uint32_t)NN + (uint32_t)sd.y;
        atomicOr(&bmap[idx >> 5], 1u << (idx & 31));
    }
    __syncthreads();

    // probe e2
    for (int i = t; i < n2; i += 1024) {
        int2 sd = b2[b * CAPE + i];
        uint32_t idx = (uint32_t)(sd.x & ROWMASK) * (uint32_t)NN + (uint32_t)sd.y;
        uint32_t m = 1u << (idx & 31);
        if (bmap[idx >> 5] & m) {
            uint32_t old = atomicAnd(&bmap[idx >> 5], ~m);
            if (old & m) {
                int p = atomicAdd(&pc, 1);
                if (p < PCAP) pass[p] = sd;
            }
        }
    }
    __syncthreads();
    if (t == 0) {
        int k = min(pc, PCAP);
        pbase = atomicAdd(c2, k);
        pc = k;
    }
    __syncthreads();
    for (int i = t; i < pc; i += 1024) {
        int p = pbase + i;
        if (p < LCAP) l2[p] = pass[i];
    }
}

// ---- scatter (unchanged logic) --------------------------------------------
__device__ inline void scatter_a1_body(const int2* __restrict__ list, int n,
                                       const float* __restrict__ x,
                                       float* __restrict__ z,
                                       int b0, int nb) {
    int c = threadIdx.x;
    for (int e = b0; e < n; e += nb) {
        int2 sd = list[e];
        atomicAdd(&z[sd.y * DD + c], x[sd.x * DD + c]);
    }
}

__device__ inline void scatter_a2_body(const int2* __restrict__ list, int n,
                                       const float* __restrict__ x,
                                       const float* __restrict__ M,
                                       const float* __restrict__ Wv,
                                       float* __restrict__ x2,
                                       int b0, int nb,
                                       float* xs, float* xd, float* red) {
    int c = threadIdx.x;
    for (int e = b0; e < n; e += nb) {
        int2 sd = list[e];            // s = source j, d = target i
        __syncthreads();
        xs[c] = x[sd.x * DD + c];
        xd[c] = x[sd.y * DD + c];
        __syncthreads();
        float acc = 0.f;
#pragma unroll 8
        for (int a = 0; a < DD; ++a)
            acc += xd[a] * M[a * DD + c];
        float part = acc * xs[c];
        for (int off = 32; off; off >>= 1)
            part += __shfl_down(part, off, 64);
        if ((c & 63) == 0) red[c >> 6] = part;
        __syncthreads();
        float s_e = red[0] + red[1];
        float v = 0.f;
#pragma unroll 8
        for (int b = 0; b < DD; ++b)
            v += Wv[c * DD + b] * xs[b];
        atomicAdd(&x2[sd.y * DD + c], s_e * v);
    }
}

__global__ void scatter_both(const int2* __restrict__ l1, const int* __restrict__ c1,
                             const int2* __restrict__ l2, const int* __restrict__ c2,
                             const float* __restrict__ x, const float* __restrict__ M,
                             const float* __restrict__ Wv,
                             float* __restrict__ z, float* __restrict__ x2) {
    __shared__ float xs[DD], xd[DD], red[2];
    if (blockIdx.x < 1024) {
        scatter_a1_body(l1, *c1, x, z, blockIdx.x, 1024);
    } else {
        scatter_a2_body(l2, *c2, x, M, Wv, x2, blockIdx.x - 1024, 1024, xs, xd, red);
    }
}

// ---- epilogue (unchanged) --------------------------------------------------
__device__ inline bf16x8 ld_bf16x8(const float* __restrict__ p) {
    float4 u0 = *(const float4*)p;
    float4 u1 = *(const float4*)(p + 4);
    bf16x8 r;
    r[0] = (__bf16)u0.x; r[1] = (__bf16)u0.y; r[2] = (__bf16)u0.z; r[3] = (__bf16)u0.w;
    r[4] = (__bf16)u1.x; r[5] = (__bf16)u1.y; r[6] = (__bf16)u1.z; r[7] = (__bf16)u1.w;
    return r;
}

__global__ __launch_bounds__(256) void epilogue_mfma(
    const float* __restrict__ x, const float* __restrict__ z,
    const float* __restrict__ x2,
    const float* __restrict__ Wg0, const float* __restrict__ Wg1,
    const int* __restrict__ cnt2, float inv_np1, float coef_x,
    float* __restrict__ out) {
    int lane = threadIdx.x & 63;
    int wave = threadIdx.x >> 6;       // 0..3 -> 32-col strip
    int i16  = lane & 15;
    int kg   = lane >> 4;              // k-group of 8
    int rowbase = blockIdx.x * 16;
    int colbase = wave * 32;

    f32x4 acc[2] = {};
#pragma unroll
    for (int kk = 0; kk < 8; ++kk) {
        const float* src = (kk < 4) ? x : z;
        const float* W   = (kk < 4) ? Wg0 : Wg1;
        int kofs = (kk & 3) * 32 + kg * 8;
        bf16x8 a  = ld_bf16x8(src + (rowbase + i16) * DD + kofs);
        bf16x8 b0 = ld_bf16x8(W + (colbase +      i16) * DD + kofs);
        bf16x8 b1 = ld_bf16x8(W + (colbase + 16 + i16) * DD + kofs);
        acc[0] = __builtin_amdgcn_mfma_f32_16x16x32_bf16(a, b0, acc[0], 0, 0, 0);
        acc[1] = __builtin_amdgcn_mfma_f32_16x16x32_bf16(a, b1, acc[1], 0, 0, 0);
    }
    float scale2 = (float)NN / (float)(*cnt2);
#pragma unroll
    for (int t = 0; t < 2; ++t)
#pragma unroll
        for (int r = 0; r < 4; ++r) {
            int row = rowbase + kg * 4 + r;
            int col = colbase + t * 16 + i16;
            float xv  = x[row * DD + col];
            float x2v = x2[row * DD + col];
            out[row * DD + col] = acc[t][r] * inv_np1 + coef_x * xv - x2v * scale2;
        }
}

// ---- host ------------------------------------------------------------------

extern "C" void kernel_launch(void* const* d_in, const int* in_sizes, int n_in,
                              void* d_out, int out_size, void* d_ws, size_t ws_size,
                              hipStream_t stream) {
    const float* x   = (const float*)d_in[0];
    const int* ei1   = (const int*)d_in[1];
    const int* ei2   = (const int*)d_in[2];
    const int* mask  = (const int*)d_in[3];
    const float* Wg0 = (const float*)d_in[4];
    const float* Wg1 = (const float*)d_in[5];
    const float* Wq  = (const float*)d_in[6];
    const float* Wk  = (const float*)d_in[7];
    const float* Wv  = (const float*)d_in[8];
    float* out = (float*)d_out;

    int e1 = in_sizes[1] / 2;
    int e2 = in_sizes[2] / 2;
    int em = in_sizes[3] / 2;
    float np1 = (float)em / (float)NN;   // 64.0 here
    float inv1 = 1.0f / np1;
    float coefx = (np1 - 1.0f) * inv1;

    char* ws = (char*)d_ws;

    // layout (all offsets 64B-aligned)
    const size_t O_Z    = 0;                       // 4 MB   (zeroed)
    const size_t O_X2   = 4194304;                 // 4 MB   (zeroed)
    const size_t O_CUR  = 8388608;                 // 768*16*4 = 49152 (zeroed)
    const size_t O_CNT  = 8437760;                 // c1,c2 (+pad to 64) (zeroed)
    const size_t O_M    = 8437824;                 // 64 KB
    const size_t O_BM   = 8503360;                 // 256*4096*8 = 8 MB
    const size_t O_B1   = 16891968;                // 256*2048*8 = 4 MB
    const size_t O_B2   = 21086272;                // 4 MB
    const size_t O_L1   = 25280576;                // 32768*8 = 256 KB
    const size_t O_L2   = 25542720;                // 256 KB
    // end = 25804864 (~24.6 MB)

    float*    z     = (float*)(ws + O_Z);
    float*    x2acc = (float*)(ws + O_X2);
    int*      curs  = (int*)(ws + O_CUR);
    int*      c1    = (int*)(ws + O_CNT);
    int*      c2    = (int*)(ws + O_CNT + 4);
    float*    M     = (float*)(ws + O_M);
    int2*     bm    = (int2*)(ws + O_BM);
    int2*     b1    = (int2*)(ws + O_B1);
    int2*     b2    = (int2*)(ws + O_B2);
    int2*     l1    = (int2*)(ws + O_L1);
    int2*     l2    = (int2*)(ws + O_L2);

    // zero z, x2, cursors, counters in one memset (bucket arrays need no clear)
    hipMemsetAsync(ws, 0, O_M, stream);

    int nbm = (em + CHUNK - 1) / CHUNK;
    int nb1 = (e1 + CHUNK - 1) / CHUNK;
    int nb2 = (e2 + CHUNK - 1) / CHUNK;
    partition_gemm<<<64 + nbm + nb1 + nb2, TPB, 0, stream>>>(
        ei1, e1, ei2, e2, mask, em, Wq, Wk, M, bm, b1, b2, curs, nbm, nb1, nb2);
    bucket_filter<<<NBUCK, 1024, 0, stream>>>(bm, b1, b2, curs, l1, c1, l2, c2);
    scatter_both<<<2048, DD, 0, stream>>>(l1, c1, l2, c2, x, M, Wv, z, x2acc);
    epilogue_mfma<<<NN / 16, 256, 0, stream>>>(x, z, x2acc, Wg0, Wg1, c2,
                                               inv1, coefx, out);
}

// Round 3
// 73.831 us; speedup vs baseline: 2.2282x; 1.0076x over previous
//
#include <hip/hip_runtime.h>
#include <hip/hip_bf16.h>
#include <stdint.h>

#define NN 8192
#define DD 128

// bucketing: bucket = s >> 5  (256 buckets of 32 rows)
#define NBUCK 256
#define ROWMASK 31
#define BSHIFT 5
#define CAPM 4096          // mask edges per bucket (mean 2048)
#define CAPE 2048          // e1/e2 edges per bucket (mean 1024)
#define CSTRIDE 16         // cursor padding: one counter per 64B line
#define LCAP 32768         // global passer-list capacity

// partition params
#define CHUNK 4096
#define TPB 256            // == NBUCK (scan uses all threads)
#define EPT 16             // edges per thread: CHUNK / TPB

#define PCAP 256           // per-block passer staging in filter

// zeroed region: [0, 8437824) = z(4MB) + x2(4MB) + cursors(48KB) + counters
#define ZERO_BYTES 8437824
#define ZERO_F4    (ZERO_BYTES / 16)

typedef __bf16 bf16x8 __attribute__((ext_vector_type(8)));
typedef float  f32x4  __attribute__((ext_vector_type(4)));

// ---- kernel 0: fast workspace zero ----------------------------------------
__global__ __launch_bounds__(256) void zero_ws(float4* __restrict__ p) {
    int stride = gridDim.x * 256;
    for (int i = blockIdx.x * 256 + threadIdx.x; i < ZERO_F4; i += stride)
        p[i] = make_float4(0.f, 0.f, 0.f, 0.f);
}

// ---- kernel 1: fused  M = Wq^T @ Wk  (blocks 0..63)  +  radix partition ---
__global__ __launch_bounds__(256) void partition_gemm(
    const int* __restrict__ ei1, int e1,
    const int* __restrict__ ei2, int e2,
    const int* __restrict__ mask, int em,
    const float* __restrict__ Wq, const float* __restrict__ Wk,
    float* __restrict__ M,
    int2* __restrict__ bm, int2* __restrict__ b1, int2* __restrict__ b2,
    int* __restrict__ cursors, int nbm, int nb1, int nb2) {
    if (blockIdx.x < 64) {
        int c = blockIdx.x * 2 + (threadIdx.x >> 7);
        int e = threadIdx.x & 127;
        float acc = 0.f;
#pragma unroll 8
        for (int a = 0; a < DD; ++a)
            acc += Wq[a * DD + c] * Wk[a * DD + e];
        M[c * DD + e] = acc;
        return;
    }
    int pb = blockIdx.x - 64;
    const int* src; int ne; int2* dst; int cap; int list; int chunk0;
    if (pb < nbm)            { src = mask; ne = em; dst = bm; cap = CAPM; list = 0; chunk0 = pb; }
    else if (pb < nbm + nb1) { src = ei1;  ne = e1; dst = b1; cap = CAPE; list = 1; chunk0 = pb - nbm; }
    else if (pb < nbm + nb1 + nb2) { src = ei2; ne = e2; dst = b2; cap = CAPE; list = 2; chunk0 = pb - nbm - nb1; }
    else return;

    int base = chunk0 * CHUNK;
    int n = ne - base;
    if (n > CHUNK) n = CHUNK;
    if (n <= 0) return;
    int t = threadIdx.x;

    __shared__ int cnt[NBUCK];
    __shared__ int sc[2][NBUCK];
    __shared__ int startS[NBUCK];
    __shared__ int gbase[NBUCK];
    __shared__ int cur[NBUCK];
    __shared__ int2 stage[CHUNK];

    cnt[t] = 0;
    __syncthreads();

    int ss[EPT], dd2[EPT];
#pragma unroll
    for (int k = 0; k < EPT; ++k) {
        int i = t + k * TPB;
        if (i < n) {
            int e = base + i;
            ss[k]  = src[e];
            dd2[k] = src[ne + e];
            atomicAdd(&cnt[ss[k] >> BSHIFT], 1);
        } else ss[k] = -1;
    }
    __syncthreads();

    // inclusive scan over 256 bucket counts (256 threads)
    sc[0][t] = cnt[t];
    __syncthreads();
    int sb = 0;
    for (int off = 1; off < NBUCK; off <<= 1) {
        int d = sb ^ 1;
        sc[d][t] = (t >= off) ? sc[sb][t] + sc[sb][t - off] : sc[sb][t];
        sb = d;
        __syncthreads();
    }
    int startv = (t == 0) ? 0 : sc[sb][t - 1];
    startS[t] = startv;
    cur[t]    = startv;
    gbase[t]  = atomicAdd(&cursors[(list * NBUCK + t) * CSTRIDE], cnt[t]);
    __syncthreads();

    // scatter into bucket-sorted LDS staging
#pragma unroll
    for (int k = 0; k < EPT; ++k) {
        if (ss[k] >= 0) {
            int b = ss[k] >> BSHIFT;
            int p = atomicAdd(&cur[b], 1);
            stage[p] = make_int2(ss[k], dd2[k]);
        }
    }
    __syncthreads();

    // coalesced flush: contiguous runs per bucket
    for (int i = t; i < n; i += TPB) {
        int2 it = stage[i];
        int b = it.x >> BSHIFT;
        int off = gbase[b] + (i - startS[b]);
        if (off < cap) dst[b * cap + off] = it;
    }
}

// ---- kernel 2: per-bucket LDS-bitmap filter -------------------------------
__global__ __launch_bounds__(1024) void bucket_filter(
    const int2* __restrict__ bm, const int2* __restrict__ b1,
    const int2* __restrict__ b2, const int* __restrict__ cursors,
    int2* __restrict__ l1, int* __restrict__ c1,
    int2* __restrict__ l2, int* __restrict__ c2) {
    __shared__ uint32_t bmap[8192];   // 32 rows x 8192 cols bits = 32 KB
    __shared__ int2 pass[PCAP];
    __shared__ int pc, pbase;
    int b = blockIdx.x;
    int t = threadIdx.x;
    int nm = min(cursors[b * CSTRIDE], CAPM);
    int n1 = min(cursors[(NBUCK + b) * CSTRIDE], CAPE);
    int n2 = min(cursors[(2 * NBUCK + b) * CSTRIDE], CAPE);

    for (int i = t; i < 8192; i += 1024) bmap[i] = 0;
    if (t == 0) pc = 0;
    __syncthreads();

    // build mask bitmap in LDS (duplicates harmless)
    for (int i = t; i < nm; i += 1024) {
        int2 sd = bm[b * CAPM + i];
        uint32_t idx = (uint32_t)(sd.x & ROWMASK) * (uint32_t)NN + (uint32_t)sd.y;
        atomicOr(&bmap[idx >> 5], 1u << (idx & 31));
    }
    __syncthreads();

    // probe e1; dedup by clear-on-pass (first clearer wins)
    for (int i = t; i < n1; i += 1024) {
        int2 sd = b1[b * CAPE + i];
        uint32_t idx = (uint32_t)(sd.x & ROWMASK) * (uint32_t)NN + (uint32_t)sd.y;
        uint32_t m = 1u << (idx & 31);
        if (bmap[idx >> 5] & m) {
            uint32_t old = atomicAnd(&bmap[idx >> 5], ~m);
            if (old & m) {
                int p = atomicAdd(&pc, 1);
                if (p < PCAP) pass[p] = sd;
            }
        }
    }
    __syncthreads();
    if (t == 0) {
        int k = min(pc, PCAP);
        pbase = atomicAdd(c1, k);
        pc = k;
    }
    __syncthreads();
    for (int i = t; i < pc; i += 1024) {
        int p = pbase + i;
        if (p < LCAP) l1[p] = pass[i];
    }
    __syncthreads();
    if (t == 0) pc = 0;
    // rebuild cleared mask bits
    for (int i = t; i < nm; i += 1024) {
        int2 sd = bm[b * CAPM + i];
        uint32_t idx = (uint32_t)(sd.x & ROWMASK) * (uint32_t)NN + (uint32_t)sd.y;
        atomicOr(&bmap[idx >> 5], 1u << (idx & 31));
    }
    __syncthreads();

    // probe e2
    for (int i = t; i < n2; i += 1024) {
        int2 sd = b2[b * CAPE + i];
        uint32_t idx = (uint32_t)(sd.x & ROWMASK) * (uint32_t)NN + (uint32_t)sd.y;
        uint32_t m = 1u << (idx & 31);
        if (bmap[idx >> 5] & m) {
            uint32_t old = atomicAnd(&bmap[idx >> 5], ~m);
            if (old & m) {
                int p = atomicAdd(&pc, 1);
                if (p < PCAP) pass[p] = sd;
            }
        }
    }
    __syncthreads();
    if (t == 0) {
        int k = min(pc, PCAP);
        pbase = atomicAdd(c2, k);
        pc = k;
    }
    __syncthreads();
    for (int i = t; i < pc; i += 1024) {
        int p = pbase + i;
        if (p < LCAP) l2[p] = pass[i];
    }
}

// ---- scatter (unchanged logic) --------------------------------------------
__device__ inline void scatter_a1_body(const int2* __restrict__ list, int n,
                                       const float* __restrict__ x,
                                       float* __restrict__ z,
                                       int b0, int nb) {
    int c = threadIdx.x;
    for (int e = b0; e < n; e += nb) {
        int2 sd = list[e];
        atomicAdd(&z[sd.y * DD + c], x[sd.x * DD + c]);
    }
}

__device__ inline void scatter_a2_body(const int2* __restrict__ list, int n,
                                       const float* __restrict__ x,
                                       const float* __restrict__ M,
                                       const float* __restrict__ Wv,
                                       float* __restrict__ x2,
                                       int b0, int nb,
                                       float* xs, float* xd, float* red) {
    int c = threadIdx.x;
    for (int e = b0; e < n; e += nb) {
        int2 sd = list[e];            // s = source j, d = target i
        __syncthreads();
        xs[c] = x[sd.x * DD + c];
        xd[c] = x[sd.y * DD + c];
        __syncthreads();
        float acc = 0.f;
#pragma unroll 8
        for (int a = 0; a < DD; ++a)
            acc += xd[a] * M[a * DD + c];
        float part = acc * xs[c];
        for (int off = 32; off; off >>= 1)
            part += __shfl_down(part, off, 64);
        if ((c & 63) == 0) red[c >> 6] = part;
        __syncthreads();
        float s_e = red[0] + red[1];
        float v = 0.f;
#pragma unroll 8
        for (int b = 0; b < DD; ++b)
            v += Wv[c * DD + b] * xs[b];
        atomicAdd(&x2[sd.y * DD + c], s_e * v);
    }
}

__global__ void scatter_both(const int2* __restrict__ l1, const int* __restrict__ c1,
                             const int2* __restrict__ l2, const int* __restrict__ c2,
                             const float* __restrict__ x, const float* __restrict__ M,
                             const float* __restrict__ Wv,
                             float* __restrict__ z, float* __restrict__ x2) {
    __shared__ float xs[DD], xd[DD], red[2];
    if (blockIdx.x < 1024) {
        scatter_a1_body(l1, *c1, x, z, blockIdx.x, 1024);
    } else {
        scatter_a2_body(l2, *c2, x, M, Wv, x2, blockIdx.x - 1024, 1024, xs, xd, red);
    }
}

// ---- epilogue (unchanged) --------------------------------------------------
__device__ inline bf16x8 ld_bf16x8(const float* __restrict__ p) {
    float4 u0 = *(const float4*)p;
    float4 u1 = *(const float4*)(p + 4);
    bf16x8 r;
    r[0] = (__bf16)u0.x; r[1] = (__bf16)u0.y; r[2] = (__bf16)u0.z; r[3] = (__bf16)u0.w;
    r[4] = (__bf16)u1.x; r[5] = (__bf16)u1.y; r[6] = (__bf16)u1.z; r[7] = (__bf16)u1.w;
    return r;
}

__global__ __launch_bounds__(256) void epilogue_mfma(
    const float* __restrict__ x, const float* __restrict__ z,
    const float* __restrict__ x2,
    const float* __restrict__ Wg0, const float* __restrict__ Wg1,
    const int* __restrict__ cnt2, float inv_np1, float coef_x,
    float* __restrict__ out) {
    int lane = threadIdx.x & 63;
    int wave = threadIdx.x >> 6;       // 0..3 -> 32-col strip
    int i16  = lane & 15;
    int kg   = lane >> 4;              // k-group of 8
    int rowbase = blockIdx.x * 16;
    int colbase = wave * 32;

    f32x4 acc[2] = {};
#pragma unroll
    for (int kk = 0; kk < 8; ++kk) {
        const float* src = (kk < 4) ? x : z;
        const float* W   = (kk < 4) ? Wg0 : Wg1;
        int kofs = (kk & 3) * 32 + kg * 8;
        bf16x8 a  = ld_bf16x8(src + (rowbase + i16) * DD + kofs);
        bf16x8 b0 = ld_bf16x8(W + (colbase +      i16) * DD + kofs);
        bf16x8 b1 = ld_bf16x8(W + (colbase + 16 + i16) * DD + kofs);
        acc[0] = __builtin_amdgcn_mfma_f32_16x16x32_bf16(a, b0, acc[0], 0, 0, 0);
        acc[1] = __builtin_amdgcn_mfma_f32_16x16x32_bf16(a, b1, acc[1], 0, 0, 0);
    }
    float scale2 = (float)NN / (float)(*cnt2);
#pragma unroll
    for (int t = 0; t < 2; ++t)
#pragma unroll
        for (int r = 0; r < 4; ++r) {
            int row = rowbase + kg * 4 + r;
            int col = colbase + t * 16 + i16;
            float xv  = x[row * DD + col];
            float x2v = x2[row * DD + col];
            out[row * DD + col] = acc[t][r] * inv_np1 + coef_x * xv - x2v * scale2;
        }
}

// ---- host ------------------------------------------------------------------

extern "C" void kernel_launch(void* const* d_in, const int* in_sizes, int n_in,
                              void* d_out, int out_size, void* d_ws, size_t ws_size,
                              hipStream_t stream) {
    const float* x   = (const float*)d_in[0];
    const int* ei1   = (const int*)d_in[1];
    const int* ei2   = (const int*)d_in[2];
    const int* mask  = (const int*)d_in[3];
    const float* Wg0 = (const float*)d_in[4];
    const float* Wg1 = (const float*)d_in[5];
    const float* Wq  = (const float*)d_in[6];
    const float* Wk  = (const float*)d_in[7];
    const float* Wv  = (const float*)d_in[8];
    float* out = (float*)d_out;

    int e1 = in_sizes[1] / 2;
    int e2 = in_sizes[2] / 2;
    int em = in_sizes[3] / 2;
    float np1 = (float)em / (float)NN;   // 64.0 here
    float inv1 = 1.0f / np1;
    float coefx = (np1 - 1.0f) * inv1;

    char* ws = (char*)d_ws;

    // layout (all offsets 64B-aligned)
    const size_t O_Z    = 0;                       // 4 MB   (zeroed)
    const size_t O_X2   = 4194304;                 // 4 MB   (zeroed)
    const size_t O_CUR  = 8388608;                 // 768*16*4 = 49152 (zeroed)
    const size_t O_CNT  = 8437760;                 // c1,c2 (+pad to 64) (zeroed)
    const size_t O_M    = 8437824;                 // 64 KB
    const size_t O_BM   = 8503360;                 // 256*4096*8 = 8 MB
    const size_t O_B1   = 16891968;                // 256*2048*8 = 4 MB
    const size_t O_B2   = 21086272;                // 4 MB
    const size_t O_L1   = 25280576;                // 32768*8 = 256 KB
    const size_t O_L2   = 25542720;                // 256 KB
    // end = 25804864 (~24.6 MB)

    float*    z     = (float*)(ws + O_Z);
    float*    x2acc = (float*)(ws + O_X2);
    int*      curs  = (int*)(ws + O_CUR);
    int*      c1    = (int*)(ws + O_CNT);
    int*      c2    = (int*)(ws + O_CNT + 4);
    float*    M     = (float*)(ws + O_M);
    int2*     bm    = (int2*)(ws + O_BM);
    int2*     b1    = (int2*)(ws + O_B1);
    int2*     b2    = (int2*)(ws + O_B2);
    int2*     l1    = (int2*)(ws + O_L1);
    int2*     l2    = (int2*)(ws + O_L2);

    // zero z, x2, cursors, counters with our own kernel (runtime fillBuffer
    // was 40 µs for this region at 206 GB/s — grid-stride float4 does it in ~2)
    zero_ws<<<1024, 256, 0, stream>>>((float4*)ws);

    int nbm = (em + CHUNK - 1) / CHUNK;
    int nb1 = (e1 + CHUNK - 1) / CHUNK;
    int nb2 = (e2 + CHUNK - 1) / CHUNK;
    partition_gemm<<<64 + nbm + nb1 + nb2, TPB, 0, stream>>>(
        ei1, e1, ei2, e2, mask, em, Wq, Wk, M, bm, b1, b2, curs, nbm, nb1, nb2);
    bucket_filter<<<NBUCK, 1024, 0, stream>>>(bm, b1, b2, curs, l1, c1, l2, c2);
    scatter_both<<<2048, DD, 0, stream>>>(l1, c1, l2, c2, x, M, Wv, z, x2acc);
    epilogue_mfma<<<NN / 16, 256, 0, stream>>>(x, z, x2acc, Wg0, Wg1, c2,
                                               inv1, coefx, out);
}

// Round 4
// 59.743 us; speedup vs baseline: 2.7537x; 1.2358x over previous
//
#include <hip/hip_runtime.h>
#include <hip/hip_bf16.h>
#include <stdint.h>

#define NN 8192
#define DD 128

#define NBUCK 256          // bucket = s >> 5 (32 rows per bucket)
#define BSHIFT 5
#define CHUNK 4096         // edges per partition block
#define SEGC 48            // per-(chunk,bucket) segment capacity (mean 16, P(>48)~3e-10)
#define EPT 16             // CHUNK / 256
#define PCAP 128           // per-bucket passer capacity (mean ~8)

typedef __bf16 bf16x8 __attribute__((ext_vector_type(8)));
typedef float  f32x4  __attribute__((ext_vector_type(4)));

__device__ inline bf16x8 ld_bf16x8(const float* __restrict__ p) {
    float4 u0 = *(const float4*)p;
    float4 u1 = *(const float4*)(p + 4);
    bf16x8 r;
    r[0] = (__bf16)u0.x; r[1] = (__bf16)u0.y; r[2] = (__bf16)u0.z; r[3] = (__bf16)u0.w;
    r[4] = (__bf16)u1.x; r[5] = (__bf16)u1.y; r[6] = (__bf16)u1.z; r[7] = (__bf16)u1.w;
    return r;
}

// split a fp32x8 row chunk into bf16 hi + lo residual (for ~fp32-accurate MFMA)
__device__ inline void ld_split(const float* __restrict__ p, bf16x8& h, bf16x8& l) {
    float4 u0 = *(const float4*)p;
    float4 u1 = *(const float4*)(p + 4);
    float v[8] = {u0.x, u0.y, u0.z, u0.w, u1.x, u1.y, u1.z, u1.w};
#pragma unroll
    for (int i = 0; i < 8; ++i) {
        __bf16 hh = (__bf16)v[i];
        h[i] = hh;
        l[i] = (__bf16)(v[i] - (float)hh);
    }
}

// ---- K1: M-gemm + V-gemm(split bf16) + packed radix partition + zeroing ----
// block ranges: [0,64) M | [64,576) V | [576,576+npart) partition | rest: zero
__global__ __launch_bounds__(256) void k1_prep(
    const float* __restrict__ x,
    const int* __restrict__ ei1, int e1,
    const int* __restrict__ ei2, int e2,
    const int* __restrict__ mask, int em,
    const float* __restrict__ Wq, const float* __restrict__ Wk,
    const float* __restrict__ Wv,
    float* __restrict__ M, float* __restrict__ V,
    float4* __restrict__ zx2, int* __restrict__ c2g,
    uint32_t* __restrict__ segM, uint32_t* __restrict__ seg1,
    uint32_t* __restrict__ seg2, int* __restrict__ counts,
    int nbm, int nb1, int nb2) {
    __shared__ int cnt[NBUCK];
    __shared__ int sc[2][NBUCK];
    __shared__ int startS[NBUCK];
    __shared__ int cur[NBUCK];
    __shared__ uint32_t stage[CHUNK];

    int bid = blockIdx.x;
    int t = threadIdx.x;
    int npart = nbm + nb1 + nb2;

    if (bid < 64) {
        // M = Wq^T @ Wk, fp32 (x2-path precision)
        int c = bid * 2 + (t >> 7);
        int e = t & 127;
        float acc = 0.f;
#pragma unroll 8
        for (int a = 0; a < DD; ++a)
            acc += Wq[a * DD + c] * Wk[a * DD + e];
        M[c * DD + e] = acc;
        return;
    }
    if (bid < 576) {
        // V = x @ Wv^T via 3-term split-bf16 MFMA (error ~1e-4 abs)
        int vb = bid - 64;                 // 0..511, 16 rows each
        int lane = t & 63;
        int wave = t >> 6;
        int i16 = lane & 15;
        int kg = lane >> 4;
        int rowbase = vb * 16;
        int colbase = wave * 32;
        f32x4 acc[2] = {};
#pragma unroll
        for (int kk = 0; kk < 4; ++kk) {
            int kofs = kk * 32 + kg * 8;
            bf16x8 ah, al, b0h, b0l, b1h, b1l;
            ld_split(x + (rowbase + i16) * DD + kofs, ah, al);
            ld_split(Wv + (colbase + i16) * DD + kofs, b0h, b0l);
            ld_split(Wv + (colbase + 16 + i16) * DD + kofs, b1h, b1l);
            acc[0] = __builtin_amdgcn_mfma_f32_16x16x32_bf16(ah, b0h, acc[0], 0, 0, 0);
            acc[0] = __builtin_amdgcn_mfma_f32_16x16x32_bf16(ah, b0l, acc[0], 0, 0, 0);
            acc[0] = __builtin_amdgcn_mfma_f32_16x16x32_bf16(al, b0h, acc[0], 0, 0, 0);
            acc[1] = __builtin_amdgcn_mfma_f32_16x16x32_bf16(ah, b1h, acc[1], 0, 0, 0);
            acc[1] = __builtin_amdgcn_mfma_f32_16x16x32_bf16(ah, b1l, acc[1], 0, 0, 0);
            acc[1] = __builtin_amdgcn_mfma_f32_16x16x32_bf16(al, b1h, acc[1], 0, 0, 0);
        }
#pragma unroll
        for (int t2 = 0; t2 < 2; ++t2)
#pragma unroll
            for (int r = 0; r < 4; ++r)
                V[(rowbase + kg * 4 + r) * DD + colbase + t2 * 16 + i16] = acc[t2][r];
        return;
    }
    if (bid < 576 + npart) {
        // radix partition into per-(chunk,bucket) segments, packed uint32
        int pb = bid - 576;
        const int* src; int ne, ch; uint32_t* seg; int* cnts;
        if (pb < nbm)            { src = mask; ne = em; ch = pb;             seg = segM; cnts = counts; }
        else if (pb < nbm + nb1) { src = ei1;  ne = e1; ch = pb - nbm;       seg = seg1; cnts = counts + nbm * NBUCK; }
        else                     { src = ei2;  ne = e2; ch = pb - nbm - nb1; seg = seg2; cnts = counts + (nbm + nb1) * NBUCK; }
        int base = ch * CHUNK;
        int n = ne - base;
        if (n > CHUNK) n = CHUNK;

        cnt[t] = 0;
        __syncthreads();

        uint32_t pk[EPT];
#pragma unroll
        for (int k = 0; k < EPT; ++k) {
            int i = t + k * 256;
            if (i < n) {
                int s = src[base + i];
                int d = src[ne + base + i];
                pk[k] = ((uint32_t)s << 13) | (uint32_t)d;
                atomicAdd(&cnt[pk[k] >> 18], 1);
            } else pk[k] = 0xFFFFFFFFu;
        }
        __syncthreads();

        // inclusive scan of cnt
        sc[0][t] = cnt[t];
        __syncthreads();
        int sb = 0;
        for (int off = 1; off < NBUCK; off <<= 1) {
            int d2 = sb ^ 1;
            sc[d2][t] = (t >= off) ? sc[sb][t] + sc[sb][t - off] : sc[sb][t];
            sb = d2;
            __syncthreads();
        }
        int startv = (t == 0) ? 0 : sc[sb][t - 1];
        startS[t] = startv;
        cur[t] = startv;
        cnts[ch * NBUCK + t] = min(cnt[t], SEGC);
        __syncthreads();

        // bucket-sort into LDS
#pragma unroll
        for (int k = 0; k < EPT; ++k) {
            if (pk[k] != 0xFFFFFFFFu) {
                int b = pk[k] >> 18;
                int p = atomicAdd(&cur[b], 1);
                stage[p] = pk[k];
            }
        }
        __syncthreads();

        // coalesced flush to deterministic segments
        for (int i = t; i < n; i += 256) {
            uint32_t v = stage[i];
            int b = v >> 18;
            int off = i - startS[b];
            if (off < SEGC) seg[(ch * NBUCK + b) * SEGC + off] = v;
        }
        return;
    }
    // zero blocks: z + x2 (8 MB = 524288 float4) and c2
    int zb = bid - (576 + npart);
    if (zb == 0 && t == 0) *c2g = 0;
    int idx = zb * 256 + t;
    int stride = 128 * 256;
    for (int i = idx; i < 524288; i += stride)
        zx2[i] = make_float4(0.f, 0.f, 0.f, 0.f);
}

// ---- K2: per-bucket filter + fused A1/A2 scatter ---------------------------
__global__ __launch_bounds__(1024) void k2_filter_scatter(
    const uint32_t* __restrict__ segM, const uint32_t* __restrict__ seg1,
    const uint32_t* __restrict__ seg2, const int* __restrict__ counts,
    const float* __restrict__ x, const float* __restrict__ Mg,
    const float* __restrict__ V,
    float* __restrict__ z, float* __restrict__ x2, int* __restrict__ c2g,
    int nbm, int nb1, int nb2) {
    __shared__ uint32_t bmap[8192];     // 32 rows x 8192 bits = 32 KB
    __shared__ float Ml[DD * DD];       // 64 KB
    __shared__ uint32_t pass[PCAP];
    __shared__ float xs[8][DD], xd[8][DD], red[8][2];
    __shared__ int pc;

    int b = blockIdx.x;
    int t = threadIdx.x;
    const int* cntM = counts;
    const int* cnt1 = counts + nbm * NBUCK;
    const int* cnt2 = counts + (nbm + nb1) * NBUCK;

    for (int i = t; i < DD * DD; i += 1024) Ml[i] = Mg[i];
    for (int i = t; i < 8192; i += 1024) bmap[i] = 0;
    if (t == 0) pc = 0;
    __syncthreads();

    // build mask bitmap
    int slotsM = nbm * SEGC;
    for (int i = t; i < slotsM; i += 1024) {
        int ch = i / SEGC, j = i - ch * SEGC;
        if (j < cntM[ch * NBUCK + b]) {
            uint32_t pk = segM[(ch * NBUCK + b) * SEGC + j];
            uint32_t bi = pk & 0x3FFFFu;
            atomicOr(&bmap[bi >> 5], 1u << (bi & 31));
        }
    }
    __syncthreads();

    // probe e1 (dedup by clear-on-pass)
    int slots1 = nb1 * SEGC;
    for (int i = t; i < slots1; i += 1024) {
        int ch = i / SEGC, j = i - ch * SEGC;
        if (j < cnt1[ch * NBUCK + b]) {
            uint32_t pk = seg1[(ch * NBUCK + b) * SEGC + j];
            uint32_t bi = pk & 0x3FFFFu;
            uint32_t m = 1u << (bi & 31);
            if (bmap[bi >> 5] & m) {
                uint32_t old = atomicAnd(&bmap[bi >> 5], ~m);
                if (old & m) {
                    int p = atomicAdd(&pc, 1);
                    if (p < PCAP) pass[p] = pk;
                }
            }
        }
    }
    __syncthreads();
    int np = min(pc, PCAP);
    int g = t >> 7, c = t & 127;

    // A1 scatter: z[d] += x[s], 8 edges in parallel
    for (int p0 = 0; p0 < np; p0 += 8) {
        int e = p0 + g;
        if (e < np) {
            uint32_t pk = pass[e];
            int s = pk >> 13, d = pk & 8191;
            atomicAdd(&z[d * DD + c], x[s * DD + c]);
        }
    }
    __syncthreads();
    if (t == 0) pc = 0;
    // rebuild cleared mask bits
    for (int i = t; i < slotsM; i += 1024) {
        int ch = i / SEGC, j = i - ch * SEGC;
        if (j < cntM[ch * NBUCK + b]) {
            uint32_t pk = segM[(ch * NBUCK + b) * SEGC + j];
            uint32_t bi = pk & 0x3FFFFu;
            atomicOr(&bmap[bi >> 5], 1u << (bi & 31));
        }
    }
    __syncthreads();

    // probe e2
    int slots2 = nb2 * SEGC;
    for (int i = t; i < slots2; i += 1024) {
        int ch = i / SEGC, j = i - ch * SEGC;
        if (j < cnt2[ch * NBUCK + b]) {
            uint32_t pk = seg2[(ch * NBUCK + b) * SEGC + j];
            uint32_t bi = pk & 0x3FFFFu;
            uint32_t m = 1u << (bi & 31);
            if (bmap[bi >> 5] & m) {
                uint32_t old = atomicAnd(&bmap[bi >> 5], ~m);
                if (old & m) {
                    int p = atomicAdd(&pc, 1);
                    if (p < PCAP) pass[p] = pk;
                }
            }
        }
    }
    __syncthreads();
    np = min(pc, PCAP);
    if (t == 0) atomicAdd(c2g, np);

    // A2 scatter: x2[d] += (xd @ M @ xs) * V[s]
    for (int p0 = 0; p0 < np; p0 += 8) {
        __syncthreads();
        int e = p0 + g;
        bool val = e < np;
        uint32_t pk = val ? pass[e] : 0;
        int s = pk >> 13, d = pk & 8191;
        if (val) {
            xs[g][c] = x[s * DD + c];
            xd[g][c] = x[d * DD + c];
        }
        __syncthreads();
        if (val) {
            float acc = 0.f;
#pragma unroll 8
            for (int a = 0; a < DD; ++a)
                acc += xd[g][a] * Ml[a * DD + c];
            float part = acc * xs[g][c];
            for (int off = 32; off; off >>= 1)
                part += __shfl_down(part, off, 64);
            if ((c & 63) == 0) red[g][c >> 6] = part;
        }
        __syncthreads();
        if (val) {
            float se = red[g][0] + red[g][1];
            atomicAdd(&x2[d * DD + c], se * V[s * DD + c]);
        }
    }
}

// ---- K3: epilogue (unchanged) ----------------------------------------------
__global__ __launch_bounds__(256) void epilogue_mfma(
    const float* __restrict__ x, const float* __restrict__ z,
    const float* __restrict__ x2,
    const float* __restrict__ Wg0, const float* __restrict__ Wg1,
    const int* __restrict__ cnt2, float inv_np1, float coef_x,
    float* __restrict__ out) {
    int lane = threadIdx.x & 63;
    int wave = threadIdx.x >> 6;
    int i16  = lane & 15;
    int kg   = lane >> 4;
    int rowbase = blockIdx.x * 16;
    int colbase = wave * 32;

    f32x4 acc[2] = {};
#pragma unroll
    for (int kk = 0; kk < 8; ++kk) {
        const float* src = (kk < 4) ? x : z;
        const float* W   = (kk < 4) ? Wg0 : Wg1;
        int kofs = (kk & 3) * 32 + kg * 8;
        bf16x8 a  = ld_bf16x8(src + (rowbase + i16) * DD + kofs);
        bf16x8 b0 = ld_bf16x8(W + (colbase +      i16) * DD + kofs);
        bf16x8 b1 = ld_bf16x8(W + (colbase + 16 + i16) * DD + kofs);
        acc[0] = __builtin_amdgcn_mfma_f32_16x16x32_bf16(a, b0, acc[0], 0, 0, 0);
        acc[1] = __builtin_amdgcn_mfma_f32_16x16x32_bf16(a, b1, acc[1], 0, 0, 0);
    }
    float scale2 = (float)NN / (float)(*cnt2);
#pragma unroll
    for (int t = 0; t < 2; ++t)
#pragma unroll
        for (int r = 0; r < 4; ++r) {
            int row = rowbase + kg * 4 + r;
            int col = colbase + t * 16 + i16;
            float xv  = x[row * DD + col];
            float x2v = x2[row * DD + col];
            out[row * DD + col] = acc[t][r] * inv_np1 + coef_x * xv - x2v * scale2;
        }
}

// ---- host ------------------------------------------------------------------

extern "C" void kernel_launch(void* const* d_in, const int* in_sizes, int n_in,
                              void* d_out, int out_size, void* d_ws, size_t ws_size,
                              hipStream_t stream) {
    const float* x   = (const float*)d_in[0];
    const int* ei1   = (const int*)d_in[1];
    const int* ei2   = (const int*)d_in[2];
    const int* mask  = (const int*)d_in[3];
    const float* Wg0 = (const float*)d_in[4];
    const float* Wg1 = (const float*)d_in[5];
    const float* Wq  = (const float*)d_in[6];
    const float* Wk  = (const float*)d_in[7];
    const float* Wv  = (const float*)d_in[8];
    float* out = (float*)d_out;

    int e1 = in_sizes[1] / 2;
    int e2 = in_sizes[2] / 2;
    int em = in_sizes[3] / 2;
    float np1 = (float)em / (float)NN;
    float inv1 = 1.0f / np1;
    float coefx = (np1 - 1.0f) * inv1;

    int nbm = (em + CHUNK - 1) / CHUNK;   // 128
    int nb1 = (e1 + CHUNK - 1) / CHUNK;   // 64
    int nb2 = (e2 + CHUNK - 1) / CHUNK;   // 64
    int npart = nbm + nb1 + nb2;

    char* ws = (char*)d_ws;
    // layout (64B-aligned)
    const size_t O_Z    = 0;                                   // 4 MB (zeroed in k1)
    const size_t O_X2   = 4194304;                             // 4 MB (zeroed in k1)
    const size_t O_M    = 8388608;                             // 64 KB
    const size_t O_V    = O_M + 65536;                         // 4 MB
    const size_t O_C2   = O_V + 4194304;                       // 64 B
    const size_t O_CNTS = O_C2 + 64;                           // npart*256*4
    const size_t O_SEGM = O_CNTS + (size_t)npart * NBUCK * 4;
    const size_t O_SEG1 = O_SEGM + (size_t)nbm * NBUCK * SEGC * 4;
    const size_t O_SEG2 = O_SEG1 + (size_t)nb1 * NBUCK * SEGC * 4;
    // end ≈ 25.5 MB

    float*    z     = (float*)(ws + O_Z);
    float*    x2acc = (float*)(ws + O_X2);
    float*    M     = (float*)(ws + O_M);
    float*    V     = (float*)(ws + O_V);
    int*      c2    = (int*)(ws + O_C2);
    int*      cnts  = (int*)(ws + O_CNTS);
    uint32_t* segM  = (uint32_t*)(ws + O_SEGM);
    uint32_t* seg1  = (uint32_t*)(ws + O_SEG1);
    uint32_t* seg2  = (uint32_t*)(ws + O_SEG2);

    k1_prep<<<576 + npart + 128, 256, 0, stream>>>(
        x, ei1, e1, ei2, e2, mask, em, Wq, Wk, Wv,
        M, V, (float4*)ws, c2, segM, seg1, seg2, cnts, nbm, nb1, nb2);
    k2_filter_scatter<<<NBUCK, 1024, 0, stream>>>(
        segM, seg1, seg2, cnts, x, M, V, z, x2acc, c2, nbm, nb1, nb2);
    epilogue_mfma<<<NN / 16, 256, 0, stream>>>(x, z, x2acc, Wg0, Wg1, c2,
                                               inv1, coefx, out);
}

// Round 5
// 57.902 us; speedup vs baseline: 2.8412x; 1.0318x over previous
//
#include <hip/hip_runtime.h>
#include <hip/hip_bf16.h>
#include <stdint.h>

#define NN 8192
#define DD 128

#define NBUCK 256          // bucket = s >> 5 (32 rows per bucket)
#define BSHIFT 5
#define CHUNK 4096         // edges per partition block
#define SEGC 48            // per-(chunk,bucket) segment capacity (mean 16)
#define EPT 16             // CHUNK / 256
#define PCAP 128           // per-bucket passer capacity (mean ~8)

typedef __bf16 bf16x8 __attribute__((ext_vector_type(8)));
typedef float  f32x4  __attribute__((ext_vector_type(4)));

__device__ inline bf16x8 ld_bf16x8(const float* __restrict__ p) {
    float4 u0 = *(const float4*)p;
    float4 u1 = *(const float4*)(p + 4);
    bf16x8 r;
    r[0] = (__bf16)u0.x; r[1] = (__bf16)u0.y; r[2] = (__bf16)u0.z; r[3] = (__bf16)u0.w;
    r[4] = (__bf16)u1.x; r[5] = (__bf16)u1.y; r[6] = (__bf16)u1.z; r[7] = (__bf16)u1.w;
    return r;
}

// split fp32x8 into bf16 hi + lo residual (3-term MFMA ~ fp32 accuracy)
__device__ inline void ld_split(const float* __restrict__ p, bf16x8& h, bf16x8& l) {
    float4 u0 = *(const float4*)p;
    float4 u1 = *(const float4*)(p + 4);
    float v[8] = {u0.x, u0.y, u0.z, u0.w, u1.x, u1.y, u1.z, u1.w};
#pragma unroll
    for (int i = 0; i < 8; ++i) {
        __bf16 hh = (__bf16)v[i];
        h[i] = hh;
        l[i] = (__bf16)(v[i] - (float)hh);
    }
}

// ---- K1: M-gemm(fp32) + packed radix partition + z/y zeroing ---------------
// blocks: [0,64) M | [64,64+npart) partition | [64+npart, +128) zero
__global__ __launch_bounds__(256) void k1_prep(
    const int* __restrict__ ei1, int e1,
    const int* __restrict__ ei2, int e2,
    const int* __restrict__ mask, int em,
    const float* __restrict__ Wq, const float* __restrict__ Wk,
    float* __restrict__ M,
    float4* __restrict__ zy, int* __restrict__ c2g,
    uint32_t* __restrict__ segM, uint32_t* __restrict__ seg1,
    uint32_t* __restrict__ seg2, int* __restrict__ counts,
    int nbm, int nb1, int nb2) {
    __shared__ int cnt[NBUCK];
    __shared__ int sc[2][NBUCK];
    __shared__ int startS[NBUCK];
    __shared__ int cur[NBUCK];
    __shared__ uint32_t stage[CHUNK];

    int bid = blockIdx.x;
    int t = threadIdx.x;
    int npart = nbm + nb1 + nb2;

    if (bid < 64) {
        // M = Wq^T @ Wk, fp32 (x2-path precision)
        int c = bid * 2 + (t >> 7);
        int e = t & 127;
        float acc = 0.f;
#pragma unroll 8
        for (int a = 0; a < DD; ++a)
            acc += Wq[a * DD + c] * Wk[a * DD + e];
        M[c * DD + e] = acc;
        return;
    }
    if (bid < 64 + npart) {
        int pb = bid - 64;
        const int* src; int ne, ch; uint32_t* seg; int* cnts;
        if (pb < nbm)            { src = mask; ne = em; ch = pb;             seg = segM; cnts = counts; }
        else if (pb < nbm + nb1) { src = ei1;  ne = e1; ch = pb - nbm;       seg = seg1; cnts = counts + nbm * NBUCK; }
        else                     { src = ei2;  ne = e2; ch = pb - nbm - nb1; seg = seg2; cnts = counts + (nbm + nb1) * NBUCK; }
        int base = ch * CHUNK;
        int n = ne - base;
        if (n > CHUNK) n = CHUNK;

        cnt[t] = 0;
        __syncthreads();

        uint32_t pk[EPT];
#pragma unroll
        for (int k = 0; k < EPT; ++k) {
            int i = t + k * 256;
            if (i < n) {
                int s = src[base + i];
                int d = src[ne + base + i];
                pk[k] = ((uint32_t)s << 13) | (uint32_t)d;
                atomicAdd(&cnt[pk[k] >> 18], 1);
            } else pk[k] = 0xFFFFFFFFu;
        }
        __syncthreads();

        // inclusive scan of cnt
        sc[0][t] = cnt[t];
        __syncthreads();
        int sb = 0;
        for (int off = 1; off < NBUCK; off <<= 1) {
            int d2 = sb ^ 1;
            sc[d2][t] = (t >= off) ? sc[sb][t] + sc[sb][t - off] : sc[sb][t];
            sb = d2;
            __syncthreads();
        }
        int startv = (t == 0) ? 0 : sc[sb][t - 1];
        startS[t] = startv;
        cur[t] = startv;
        cnts[ch * NBUCK + t] = min(cnt[t], SEGC);
        __syncthreads();

        // bucket-sort into LDS
#pragma unroll
        for (int k = 0; k < EPT; ++k) {
            if (pk[k] != 0xFFFFFFFFu) {
                int b = pk[k] >> 18;
                int p = atomicAdd(&cur[b], 1);
                stage[p] = pk[k];
            }
        }
        __syncthreads();

        // coalesced flush to deterministic segments
        for (int i = t; i < n; i += 256) {
            uint32_t v = stage[i];
            int b = v >> 18;
            int off = i - startS[b];
            if (off < SEGC) seg[(ch * NBUCK + b) * SEGC + off] = v;
        }
        return;
    }
    // zero blocks: z + y (8 MB = 524288 float4) and c2
    int zb = bid - (64 + npart);
    if (zb == 0 && t == 0) *c2g = 0;
    int idx = zb * 256 + t;
    int stride = 128 * 256;
    for (int i = idx; i < 524288; i += stride)
        zy[i] = make_float4(0.f, 0.f, 0.f, 0.f);
}

// ---- K2: per-bucket filter + fused A1/A2 scatter ---------------------------
// A2 accumulates y[d] += s_e * x[s]  (Wv^T applied in epilogue)
__global__ __launch_bounds__(1024) void k2_filter_scatter(
    const uint32_t* __restrict__ segM, const uint32_t* __restrict__ seg1,
    const uint32_t* __restrict__ seg2, const int* __restrict__ counts,
    const float* __restrict__ x, const float* __restrict__ Mg,
    float* __restrict__ z, float* __restrict__ y, int* __restrict__ c2g,
    int nbm, int nb1, int nb2) {
    __shared__ uint32_t bmap[8192];     // 32 KB
    __shared__ uint32_t seen[8192];     // 32 KB
    __shared__ uint32_t pass[PCAP];
    __shared__ float xs[8][DD], xd[8][DD], red[8][2];
    __shared__ int pc;

    int b = blockIdx.x;
    int t = threadIdx.x;
    const int* cntM = counts;
    const int* cnt1 = counts + nbm * NBUCK;
    const int* cnt2 = counts + (nbm + nb1) * NBUCK;

    for (int i = t; i < 8192; i += 1024) { bmap[i] = 0; seen[i] = 0; }
    if (t == 0) pc = 0;
    __syncthreads();

    // build mask bitmap (duplicates harmless)
    int slotsM = nbm * SEGC;
    for (int i = t; i < slotsM; i += 1024) {
        int ch = i / SEGC, j = i - ch * SEGC;
        if (j < cntM[ch * NBUCK + b]) {
            uint32_t pk = segM[(ch * NBUCK + b) * SEGC + j];
            uint32_t bi = pk & 0x3FFFFu;
            atomicOr(&bmap[bi >> 5], 1u << (bi & 31));
        }
    }
    __syncthreads();

    // probe e1; dedup via seen bitmap (bmap stays intact -> no rebuild)
    int slots1 = nb1 * SEGC;
    for (int i = t; i < slots1; i += 1024) {
        int ch = i / SEGC, j = i - ch * SEGC;
        if (j < cnt1[ch * NBUCK + b]) {
            uint32_t pk = seg1[(ch * NBUCK + b) * SEGC + j];
            uint32_t bi = pk & 0x3FFFFu;
            uint32_t m = 1u << (bi & 31);
            if (bmap[bi >> 5] & m) {
                uint32_t old = atomicOr(&seen[bi >> 5], m);
                if (!(old & m)) {
                    int p = atomicAdd(&pc, 1);
                    if (p < PCAP) pass[p] = pk;
                }
            }
        }
    }
    __syncthreads();
    int np = min(pc, PCAP);
    int g = t >> 7, c = t & 127;

    // A1 scatter: z[d] += x[s], 8 edges in parallel
    for (int p0 = 0; p0 < np; p0 += 8) {
        int e = p0 + g;
        if (e < np) {
            uint32_t pk = pass[e];
            int s = pk >> 13, d = pk & 8191;
            atomicAdd(&z[d * DD + c], x[s * DD + c]);
        }
    }
    __syncthreads();
    if (t == 0) pc = 0;
    for (int i = t; i < 8192; i += 1024) seen[i] = 0;
    __syncthreads();

    // probe e2
    int slots2 = nb2 * SEGC;
    for (int i = t; i < slots2; i += 1024) {
        int ch = i / SEGC, j = i - ch * SEGC;
        if (j < cnt2[ch * NBUCK + b]) {
            uint32_t pk = seg2[(ch * NBUCK + b) * SEGC + j];
            uint32_t bi = pk & 0x3FFFFu;
            uint32_t m = 1u << (bi & 31);
            if (bmap[bi >> 5] & m) {
                uint32_t old = atomicOr(&seen[bi >> 5], m);
                if (!(old & m)) {
                    int p = atomicAdd(&pc, 1);
                    if (p < PCAP) pass[p] = pk;
                }
            }
        }
    }
    __syncthreads();
    np = min(pc, PCAP);
    if (t == 0) atomicAdd(c2g, np);

    // A2 scatter: y[d] += (x[d] @ M @ x[s]) * x[s]
    for (int p0 = 0; p0 < np; p0 += 8) {
        __syncthreads();
        int e = p0 + g;
        bool val = e < np;
        uint32_t pk = val ? pass[e] : 0;
        int s = pk >> 13, d = pk & 8191;
        if (val) {
            xs[g][c] = x[s * DD + c];
            xd[g][c] = x[d * DD + c];
        }
        __syncthreads();
        if (val) {
            float acc = 0.f;
#pragma unroll 8
            for (int a = 0; a < DD; ++a)
                acc += xd[g][a] * Mg[a * DD + c];   // coalesced, L2-resident
            float part = acc * xs[g][c];
            for (int off = 32; off; off >>= 1)
                part += __shfl_down(part, off, 64);
            if ((c & 63) == 0) red[g][c >> 6] = part;
        }
        __syncthreads();
        if (val) {
            float se = red[g][0] + red[g][1];
            atomicAdd(&y[d * DD + c], se * xs[g][c]);
        }
    }
}

// ---- K3: epilogue, now fusing x2 = y @ Wv^T (split-bf16) -------------------
__global__ __launch_bounds__(256) void epilogue_mfma(
    const float* __restrict__ x, const float* __restrict__ z,
    const float* __restrict__ y, const float* __restrict__ Wv,
    const float* __restrict__ Wg0, const float* __restrict__ Wg1,
    const int* __restrict__ cnt2, float inv_np1, float coef_x,
    float* __restrict__ out) {
    int lane = threadIdx.x & 63;
    int wave = threadIdx.x >> 6;
    int i16  = lane & 15;
    int kg   = lane >> 4;
    int rowbase = blockIdx.x * 16;
    int colbase = wave * 32;

    f32x4 acc[2] = {}, acc2[2] = {};
#pragma unroll
    for (int kk = 0; kk < 8; ++kk) {
        const float* src = (kk < 4) ? x : z;
        const float* W   = (kk < 4) ? Wg0 : Wg1;
        int kofs = (kk & 3) * 32 + kg * 8;
        bf16x8 a  = ld_bf16x8(src + (rowbase + i16) * DD + kofs);
        bf16x8 b0 = ld_bf16x8(W + (colbase +      i16) * DD + kofs);
        bf16x8 b1 = ld_bf16x8(W + (colbase + 16 + i16) * DD + kofs);
        acc[0] = __builtin_amdgcn_mfma_f32_16x16x32_bf16(a, b0, acc[0], 0, 0, 0);
        acc[1] = __builtin_amdgcn_mfma_f32_16x16x32_bf16(a, b1, acc[1], 0, 0, 0);
    }
    // x2-tile = y @ Wv^T via 3-term split-bf16
#pragma unroll
    for (int kk = 0; kk < 4; ++kk) {
        int kofs = kk * 32 + kg * 8;
        bf16x8 yh, yl, w0h, w0l, w1h, w1l;
        ld_split(y + (rowbase + i16) * DD + kofs, yh, yl);
        ld_split(Wv + (colbase +      i16) * DD + kofs, w0h, w0l);
        ld_split(Wv + (colbase + 16 + i16) * DD + kofs, w1h, w1l);
        acc2[0] = __builtin_amdgcn_mfma_f32_16x16x32_bf16(yh, w0h, acc2[0], 0, 0, 0);
        acc2[0] = __builtin_amdgcn_mfma_f32_16x16x32_bf16(yh, w0l, acc2[0], 0, 0, 0);
        acc2[0] = __builtin_amdgcn_mfma_f32_16x16x32_bf16(yl, w0h, acc2[0], 0, 0, 0);
        acc2[1] = __builtin_amdgcn_mfma_f32_16x16x32_bf16(yh, w1h, acc2[1], 0, 0, 0);
        acc2[1] = __builtin_amdgcn_mfma_f32_16x16x32_bf16(yh, w1l, acc2[1], 0, 0, 0);
        acc2[1] = __builtin_amdgcn_mfma_f32_16x16x32_bf16(yl, w1h, acc2[1], 0, 0, 0);
    }
    float scale2 = (float)NN / (float)(*cnt2);
#pragma unroll
    for (int t = 0; t < 2; ++t)
#pragma unroll
        for (int r = 0; r < 4; ++r) {
            int row = rowbase + kg * 4 + r;
            int col = colbase + t * 16 + i16;
            float xv = x[row * DD + col];
            out[row * DD + col] = acc[t][r] * inv_np1 + coef_x * xv
                                - acc2[t][r] * scale2;
        }
}

// ---- host ------------------------------------------------------------------

extern "C" void kernel_launch(void* const* d_in, const int* in_sizes, int n_in,
                              void* d_out, int out_size, void* d_ws, size_t ws_size,
                              hipStream_t stream) {
    const float* x   = (const float*)d_in[0];
    const int* ei1   = (const int*)d_in[1];
    const int* ei2   = (const int*)d_in[2];
    const int* mask  = (const int*)d_in[3];
    const float* Wg0 = (const float*)d_in[4];
    const float* Wg1 = (const float*)d_in[5];
    const float* Wq  = (const float*)d_in[6];
    const float* Wk  = (const float*)d_in[7];
    const float* Wv  = (const float*)d_in[8];
    float* out = (float*)d_out;

    int e1 = in_sizes[1] / 2;
    int e2 = in_sizes[2] / 2;
    int em = in_sizes[3] / 2;
    float np1 = (float)em / (float)NN;
    float inv1 = 1.0f / np1;
    float coefx = (np1 - 1.0f) * inv1;

    int nbm = (em + CHUNK - 1) / CHUNK;   // 128
    int nb1 = (e1 + CHUNK - 1) / CHUNK;   // 64
    int nb2 = (e2 + CHUNK - 1) / CHUNK;   // 64
    int npart = nbm + nb1 + nb2;

    char* ws = (char*)d_ws;
    const size_t O_Z    = 0;                                   // 4 MB (zeroed in k1)
    const size_t O_Y    = 4194304;                             // 4 MB (zeroed in k1)
    const size_t O_M    = 8388608;                             // 64 KB
    const size_t O_C2   = O_M + 65536;                         // 64 B
    const size_t O_CNTS = O_C2 + 64;                           // npart*256*4
    const size_t O_SEGM = O_CNTS + (size_t)npart * NBUCK * 4;
    const size_t O_SEG1 = O_SEGM + (size_t)nbm * NBUCK * SEGC * 4;
    const size_t O_SEG2 = O_SEG1 + (size_t)nb1 * NBUCK * SEGC * 4;
    // end ≈ 21.3 MB

    float*    z     = (float*)(ws + O_Z);
    float*    y     = (float*)(ws + O_Y);
    float*    M     = (float*)(ws + O_M);
    int*      c2    = (int*)(ws + O_C2);
    int*      cnts  = (int*)(ws + O_CNTS);
    uint32_t* segM  = (uint32_t*)(ws + O_SEGM);
    uint32_t* seg1  = (uint32_t*)(ws + O_SEG1);
    uint32_t* seg2  = (uint32_t*)(ws + O_SEG2);

    k1_prep<<<64 + npart + 128, 256, 0, stream>>>(
        ei1, e1, ei2, e2, mask, em, Wq, Wk,
        M, (float4*)ws, c2, segM, seg1, seg2, cnts, nbm, nb1, nb2);
    k2_filter_scatter<<<NBUCK, 1024, 0, stream>>>(
        segM, seg1, seg2, cnts, x, M, z, y, c2, nbm, nb1, nb2);
    epilogue_mfma<<<NN / 16, 256, 0, stream>>>(x, z, y, Wv, Wg0, Wg1, c2,
                                               inv1, coefx, out);
}